// Round 17
// baseline (243.723 us; speedup 1.0000x reference)
//
#include <hip/hip_runtime.h>

#define N_USER   100000
#define N_ITEM   150000
#define N_NODES  250000
#define N_HID    64
#define E_UI     1000000
#define E_S      1000000
#define N_TOT    (N_NODES + N_USER)      // 350000
#define E_TOT    (E_UI + E_S)            // 2000000

#define BR     64                         // rows per block (spmm)
#define CH     8192                       // edges per binning chunk
#define NBBIN  ((E_TOT + CH - 1) / CH)    // 245
#define RPB    1024                       // rows per coarse bucket
#define RPB_SH 10
#define NBKT   ((N_TOT + RPB - 1) / RPB)  // 342
#define NBKTP  512                        // padded bucket-array size
#define LSTR   344                        // lstartAll row stride (ints)
#define ASTR   72                         // agg LDS row stride (shorts, 144B)
#define BCAP_PAD 16384                    // per-bucket pairs capacity (padded to 4)
#define BCAP_STD 12288                    // per-bucket pairs capacity (unpadded)

typedef unsigned long long ull;
typedef __attribute__((ext_vector_type(8))) short short8v;   // 8 bf16 (4 VGPR)
typedef __attribute__((ext_vector_type(4))) float f32x4;

__device__ __forceinline__ unsigned short f_to_bf(float f) {
    unsigned u = __float_as_uint(f);
    u += 0x7FFF + ((u >> 16) & 1);
    return (unsigned short)(u >> 16);
}
__device__ __forceinline__ float bf_to_f(unsigned short s) {
    return __uint_as_float((unsigned)s << 16);
}
__device__ __forceinline__ unsigned pack_bf2(float a, float b) {
    return (unsigned)f_to_bf(a) | ((unsigned)f_to_bf(b) << 16);
}

// ===========================================================================
// bin_embcast: heterogeneous grid.
//   blocks [0, NBBIN):  per-block private bucket-grouping (zero global atomics)
//   blocks [NBBIN, ..): bf16 cast -> embBf[350K][64] (combined index space)
// ===========================================================================
__global__ __launch_bounds__(512) void bin_embcast(const int* __restrict__ ui_rows,
                                                   const int* __restrict__ ui_cols,
                                                   const float* __restrict__ ui_vals,
                                                   const int* __restrict__ s_rows,
                                                   const int* __restrict__ s_cols,
                                                   const float* __restrict__ s_vals,
                                                   ull* __restrict__ pairsA,
                                                   int* __restrict__ lstartAll,
                                                   const float* __restrict__ u,
                                                   const float* __restrict__ it,
                                                   unsigned short* __restrict__ embBf) {
    __shared__ int hist[NBKTP];
    __shared__ int lstart[NBKTP];
    __shared__ int cnt2[NBKTP];
    const int t = threadIdx.x;

    if ((int)blockIdx.x >= NBBIN) {                 // ---- embcast part ----
        int i = ((int)blockIdx.x - NBBIN) * 512 + t;   // 8 shorts per thread
        const int n8 = N_TOT * N_HID / 8;              // 2.8M
        if (i >= n8) return;
        size_t base = (size_t)i * 8;
        const size_t nu = (size_t)N_USER * N_HID;
        const size_t nn = (size_t)N_NODES * N_HID;
        const float* src = (base < nu) ? u + base
                         : (base < nn) ? it + (base - nu)
                                       : u + (base - nn);
        float4 a = *(const float4*)src;
        float4 b = *(const float4*)(src + 4);
        uint4 o;
        o.x = pack_bf2(a.x, a.y); o.y = pack_bf2(a.z, a.w);
        o.z = pack_bf2(b.x, b.y); o.w = pack_bf2(b.z, b.w);
        *(uint4*)&embBf[base] = o;
        return;
    }

    // ---- binning part ----
    hist[t] = 0; cnt2[t] = 0;
    __syncthreads();

    const int e0 = blockIdx.x * CH;
    const int n  = min(CH, E_TOT - e0);

    // phase 1: bucket histogram (LDS atomics only)
    for (int i = t; i < n; i += 512) {
        int g = e0 + i, r;
        if (g < E_UI) r = ui_rows[g];
        else          r = N_NODES + s_rows[g - E_UI];
        atomicAdd(&hist[r >> RPB_SH], 1);
    }
    __syncthreads();

    // 512-wide exclusive scan (1 elem/thread)
    int v = hist[t];
    lstart[t] = v;
    __syncthreads();
    for (int off = 1; off < NBKTP; off <<= 1) {
        int a = (t >= off) ? lstart[t - off] : 0;
        __syncthreads();
        lstart[t] += a;
        __syncthreads();
    }
    int ex = lstart[t] - v;
    __syncthreads();
    lstart[t] = ex;
    if (t <= NBKT) lstartAll[blockIdx.x * LSTR + t] = ex;   // [NBKT] = n
    __syncthreads();

    // phase 2: re-read + place grouped into private region
    for (int i = t; i < n; i += 512) {
        int g = e0 + i, r, c; float val;
        if (g < E_UI) { r = ui_rows[g];            c = ui_cols[g];            val = ui_vals[g]; }
        else          { int k = g - E_UI;
                        r = N_NODES + s_rows[k];   c = N_NODES + s_cols[k];   val = s_vals[k]; }
        int b = r >> RPB_SH;
        ull entry = ((ull)__float_as_uint(val) << 32) |
                    ((ull)(unsigned)(r & (RPB - 1)) << 19) | (unsigned)c;
        int l = atomicAdd(&cnt2[b], 1);
        pairsA[(size_t)blockIdx.x * CH + lstart[b] + l] = entry;
    }
}

// ===========================================================================
// fine_gather2: one block per bucket. NO global atomics, NO global scan.
//   PAD: row counts rounded to 4 (tail round of 4 in spmm is mask-free).
//   bucketEnd[b] = padded data end; last bucket writes rowStart[N_TOT].
// ===========================================================================
template <bool PAD>
__global__ __launch_bounds__(512) void fine_gather2(const ull* __restrict__ pairsA,
                                                    const int* __restrict__ lstartAll,
                                                    int* __restrict__ rowStart,
                                                    int* __restrict__ bucketEnd,
                                                    ull* __restrict__ pairs,
                                                    int bcap) {
    __shared__ int cur[RPB];       // counts -> absolute cursor starts
    __shared__ int sc[RPB];        // scan workspace -> pad-end
    const int b = blockIdx.x, t = threadIdx.x;
    const int r0 = b * RPB;
    const int nr = min(RPB, N_TOT - r0);
    const int base = b * bcap;

    cur[t] = 0; cur[t + 512] = 0;
    __syncthreads();

    const int q    = t >> 4;        // 32 quarters
    const int lane = t & 15;

    // pass A: per-row counts
    for (int blk = q; blk < NBBIN; blk += 32) {
        int s = lstartAll[blk * LSTR + b];
        int e = lstartAll[blk * LSTR + b + 1];
        const ull* src = pairsA + (size_t)blk * CH;
        for (int j = s + lane; j < e; j += 16)
            atomicAdd(&cur[(int)((src[j] >> 19) & (RPB - 1))], 1);
    }
    __syncthreads();

    // padded scan over 1024 counts (2 elems/thread, Hillis–Steele inclusive)
    int c0 = cur[t], c1 = cur[t + 512];
    int p0 = PAD ? ((c0 + 3) & ~3) : c0;
    int p1 = PAD ? ((c1 + 3) & ~3) : c1;
    sc[t] = p0; sc[t + 512] = p1;
    __syncthreads();
    for (int off = 1; off < RPB; off <<= 1) {
        int a = (t >= off) ? sc[t - off] : 0;
        int bb = (t + 512 >= off) ? sc[t + 512 - off] : 0;
        __syncthreads();
        sc[t] += a; sc[t + 512] += bb;
        __syncthreads();
    }
    int inc0 = sc[t], inc1 = sc[t + 512];
    __syncthreads();
    int st0 = base + inc0 - p0;
    int st1 = base + inc1 - p1;
    cur[t] = st0;            cur[t + 512] = st1;            // cursor starts
    sc[t]  = st0 + p0;       sc[t + 512]  = st1 + p1;       // pad-ends
    if (t < nr)        rowStart[r0 + t] = st0;
    if (t + 512 < nr)  rowStart[r0 + t + 512] = st1;
    if (t == 511) {
        bucketEnd[b] = st1 + p1;                           // bucket data end
        if (b == NBKT - 1) rowStart[N_TOT] = st1 + p1;     // global sentinel
    }
    __syncthreads();

    // pass B: scatter (segments are L2-hot from pass A)
    for (int blk = q; blk < NBBIN; blk += 32) {
        int s = lstartAll[blk * LSTR + b];
        int e = lstartAll[blk * LSTR + b + 1];
        const ull* src = pairsA + (size_t)blk * CH;
        for (int j = s + lane; j < e; j += 16) {
            ull en = src[j];
            int rLow = (int)((en >> 19) & (RPB - 1));
            int pos = atomicAdd(&cur[rLow], 1);
            pairs[pos] = (en & 0xFFFFFFFF00000000ull) | (en & 0x7FFFFull);
        }
    }
    if (PAD) {
        __syncthreads();
        for (int i = t; i < nr; i += 512) {
            int end = sc[i];
            for (int j = cur[i]; j < end; ++j) pairs[j] = 0;   // v=0, c=0
        }
    }
}

// ===========================================================================
// spmm_m: quarter-wave gather (bf16, combined index space) + MFMA W-apply.
//   PADDED: rows 4-aligned; mask-free 8-rounds + optional mask-free 4-tail.
//   (NO pairs prefetch — costs VGPR/occupancy, proven R9/R15.)
//   Bucket-boundary rows clamp their end with bucketEnd (region gaps!).
//   LAYER 1: gather embBf; tmp12 = bf16(emb+n1); B2 = bf16(lv1)
//   LAYER 2: gather B2;    out = f32(tmp12) + n2
// ===========================================================================
template <int LAYER, bool PADDED>
__global__ __launch_bounds__(256) void spmm_m(const ull* __restrict__ pairs,
                                              const int* __restrict__ rowStart,
                                              const int* __restrict__ bucketEnd,
                                              const unsigned short* __restrict__ embBf,
                                              const unsigned short* __restrict__ B2in,
                                              unsigned short* __restrict__ B2out,
                                              const unsigned short* __restrict__ tmp12in,
                                              unsigned short* __restrict__ tmp12out,
                                              const float* __restrict__ Wui,
                                              const float* __restrict__ Wsoc,
                                              float* __restrict__ out_ui,
                                              float* __restrict__ out_s,
                                              int uiBlocks) {
    __shared__ unsigned short Wb[N_HID][ASTR];        // Wb[c][r] = bf16(W[r][c])
    __shared__ unsigned short agg[4][16][ASTR];
    const int tid = threadIdx.x;
    const bool isUI = (int)blockIdx.x < uiBlocks;
    const int bl    = isUI ? blockIdx.x : blockIdx.x - uiBlocks;
    const int rbeg  = isUI ? bl * BR : N_NODES + bl * BR;
    const int rlim  = isUI ? min(BR, N_NODES - bl * BR) : min(BR, N_USER - bl * BR);

    const float* W = isUI ? Wui : Wsoc;
    for (int idx = tid; idx < N_HID * N_HID; idx += 256) {
        int r = idx >> 6, c = idx & 63;
        Wb[c][r] = f_to_bf(W[idx]);
    }
    __syncthreads();

    const int w = tid >> 6;
    if (w * 16 >= rlim) return;             // rlim is always a multiple of 16
    const int s = tid & 15;
    const int g = (tid >> 4) & 3;

    short8v bfrag[4][2];
#pragma unroll
    for (int nt = 0; nt < 4; ++nt)
#pragma unroll
        for (int kt = 0; kt < 2; ++kt)
            bfrag[nt][kt] = *(const short8v*)&Wb[nt * 16 + s][kt * 32 + g * 8];

    const unsigned short* gsrc = (LAYER == 1) ? embBf : B2in;

    int sB[4], eB[4];
#pragma unroll
    for (int i = 0; i < 4; ++i) {
        int r = rbeg + w * 16 + i * 4 + g;
        sB[i] = rowStart[r];
        int e = rowStart[r + 1];
        if (((r + 1) & (RPB - 1)) == 0)     // last row of a bucket: region gap
            e = bucketEnd[r >> RPB_SH];
        eB[i] = e;
    }

    for (int i = 0; i < 4; ++i) {
        float4 acc = make_float4(0.f, 0.f, 0.f, 0.f);
        if (PADDED) {
            int j = sB[i], e0 = eB[i];
            for (; j + 8 <= e0; j += 8) {          // mask-free 8-rounds
                ull p[8];
#pragma unroll
                for (int k = 0; k < 8; ++k) p[k] = pairs[j + k];
                ushort4 raw[8];
#pragma unroll
                for (int k = 0; k < 8; ++k)
                    raw[k] = *(const ushort4*)(gsrc +
                               (size_t)(unsigned)p[k] * N_HID + s * 4);
#pragma unroll
                for (int k = 0; k < 8; ++k) {
                    float v = __uint_as_float((unsigned)(p[k] >> 32));
                    acc.x = fmaf(v, bf_to_f(raw[k].x), acc.x);
                    acc.y = fmaf(v, bf_to_f(raw[k].y), acc.y);
                    acc.z = fmaf(v, bf_to_f(raw[k].z), acc.z);
                    acc.w = fmaf(v, bf_to_f(raw[k].w), acc.w);
                }
            }
            if (j < e0) {                          // mask-free 4-tail (exactly 4)
                ull p[4];
#pragma unroll
                for (int k = 0; k < 4; ++k) p[k] = pairs[j + k];
                ushort4 raw[4];
#pragma unroll
                for (int k = 0; k < 4; ++k)
                    raw[k] = *(const ushort4*)(gsrc +
                               (size_t)(unsigned)p[k] * N_HID + s * 4);
#pragma unroll
                for (int k = 0; k < 4; ++k) {
                    float v = __uint_as_float((unsigned)(p[k] >> 32));
                    acc.x = fmaf(v, bf_to_f(raw[k].x), acc.x);
                    acc.y = fmaf(v, bf_to_f(raw[k].y), acc.y);
                    acc.z = fmaf(v, bf_to_f(raw[k].z), acc.z);
                    acc.w = fmaf(v, bf_to_f(raw[k].w), acc.w);
                }
            }
        } else {
            int e0 = eB[i];
            for (int j = sB[i]; j < e0; j += 8) {
                int last = e0 - 1;
                ull p[8];
#pragma unroll
                for (int k = 0; k < 8; ++k) p[k] = pairs[min(j + k, last)];
                ushort4 raw[8];
#pragma unroll
                for (int k = 0; k < 8; ++k)
                    raw[k] = *(const ushort4*)(gsrc +
                               (size_t)(unsigned)p[k] * N_HID + s * 4);
#pragma unroll
                for (int k = 0; k < 8; ++k) {
                    float v = (j + k < e0) ? __uint_as_float((unsigned)(p[k] >> 32)) : 0.f;
                    acc.x = fmaf(v, bf_to_f(raw[k].x), acc.x);
                    acc.y = fmaf(v, bf_to_f(raw[k].y), acc.y);
                    acc.z = fmaf(v, bf_to_f(raw[k].z), acc.z);
                    acc.w = fmaf(v, bf_to_f(raw[k].w), acc.w);
                }
            }
        }
        uint2 pk;
        pk.x = pack_bf2(acc.x, acc.y);
        pk.y = pack_bf2(acc.z, acc.w);
        *(uint2*)&agg[w][i * 4 + g][s * 4] = pk;
    }
    asm volatile("s_waitcnt lgkmcnt(0)" ::: "memory");
    __builtin_amdgcn_sched_barrier(0);

    // ---- MFMA: z(16x64) = agg(16x64) @ W(64x64) ----
    short8v a0 = *(const short8v*)&agg[w][s][g * 8];
    short8v a1 = *(const short8v*)&agg[w][s][32 + g * 8];
    f32x4 c[4];
    const f32x4 zero4 = {0.f, 0.f, 0.f, 0.f};
#pragma unroll
    for (int nt = 0; nt < 4; ++nt) {
        c[nt] = __builtin_amdgcn_mfma_f32_16x16x32_bf16(a0, bfrag[nt][0], zero4, 0, 0, 0);
        c[nt] = __builtin_amdgcn_mfma_f32_16x16x32_bf16(a1, bfrag[nt][1], c[nt], 0, 0, 0);
    }

    // ---- leaky + row l2norm (C/D: col = nt*16+s, row = g*4+r) ----
    float lv[4][4];
    float ss[4] = {0.f, 0.f, 0.f, 0.f};
#pragma unroll
    for (int nt = 0; nt < 4; ++nt)
#pragma unroll
        for (int r = 0; r < 4; ++r) {
            float z = c[nt][r];
            float l = (z >= 0.f) ? z : 0.5f * z;
            lv[nt][r] = l;
            ss[r] = fmaf(l, l, ss[r]);
        }
#pragma unroll
    for (int r = 0; r < 4; ++r) {
        float t = ss[r];
        t += __shfl_xor(t, 1, 64);
        t += __shfl_xor(t, 2, 64);
        t += __shfl_xor(t, 4, 64);
        t += __shfl_xor(t, 8, 64);
        ss[r] = 1.f / fmaxf(sqrtf(t), 1e-12f);
    }

    // ---- outputs ----
#pragma unroll
    for (int r = 0; r < 4; ++r) {
        int R = rbeg + w * 16 + g * 4 + r;
        if (LAYER == 1) {
#pragma unroll
            for (int nt = 0; nt < 4; ++nt) {
                int col = nt * 16 + s;
                float eb = bf_to_f(embBf[(size_t)R * N_HID + col]);   // combined space
                tmp12out[(size_t)R * N_HID + col] = f_to_bf(fmaf(lv[nt][r], ss[r], eb));
                B2out[(size_t)R * N_HID + col]    = f_to_bf(lv[nt][r]);
            }
        } else {
            float* op = isUI ? out_ui + (size_t)R * N_HID
                             : out_s  + (size_t)(R - N_NODES) * N_HID;
#pragma unroll
            for (int nt = 0; nt < 4; ++nt) {
                int col = nt * 16 + s;
                float tb = bf_to_f(tmp12in[(size_t)R * N_HID + col]);
                op[col] = fmaf(lv[nt][r], ss[r], tb);
            }
        }
    }
}

// ===========================================================================
// Atomic fallback (only if ws too small for the sorted path)
// ===========================================================================
__global__ __launch_bounds__(256) void init_concat(const float* __restrict__ u,
                                                   const float* __restrict__ it,
                                                   float* __restrict__ A,
                                                   float* __restrict__ out) {
    int i = blockIdx.x * 256 + threadIdx.x;
    const int nu4 = N_USER * N_HID / 4;
    const int nt4 = N_NODES * N_HID / 4;
    if (i >= nt4) return;
    float4 v = (i < nu4) ? ((const float4*)u)[i] : ((const float4*)it)[i - nu4];
    ((float4*)A)[i]   = v;
    ((float4*)out)[i] = v;
}

__global__ __launch_bounds__(256) void copy2(const float* __restrict__ src,
                                             float* __restrict__ d0,
                                             float* __restrict__ d1, int n4) {
    int i = blockIdx.x * 256 + threadIdx.x;
    if (i >= n4) return;
    float4 v = ((const float4*)src)[i];
    ((float4*)d0)[i] = v;
    ((float4*)d1)[i] = v;
}

__global__ __launch_bounds__(256) void gemm64(const float* __restrict__ X,
                                              const float* __restrict__ W,
                                              float* __restrict__ Y, int nrows) {
    __shared__ float Ws[N_HID * N_HID];
    int tid = threadIdx.x;
#pragma unroll
    for (int c = 0; c < 16; ++c) Ws[c * 256 + tid] = W[c * 256 + tid];
    __syncthreads();
    int row = blockIdx.x * 256 + tid;
    if (row >= nrows) return;
    float x[N_HID];
    const float4* xr = (const float4*)(X + (size_t)row * N_HID);
#pragma unroll
    for (int c = 0; c < 16; ++c) {
        float4 v = xr[c];
        x[4*c+0] = v.x; x[4*c+1] = v.y; x[4*c+2] = v.z; x[4*c+3] = v.w;
    }
    float4* y4 = (float4*)(Y + (size_t)row * N_HID);
    for (int jc = 0; jc < 16; ++jc) {
        float4 a = make_float4(0.f,0.f,0.f,0.f);
#pragma unroll
        for (int k = 0; k < N_HID; ++k) {
            float4 wv = *((const float4*)&Ws[k * N_HID + jc * 4]);
            a.x += x[k]*wv.x; a.y += x[k]*wv.y; a.z += x[k]*wv.z; a.w += x[k]*wv.w;
        }
        y4[jc] = a;
    }
}

__global__ __launch_bounds__(256) void spmm_scatter(const int* __restrict__ rows,
                                                    const int* __restrict__ cols,
                                                    const float* __restrict__ vals,
                                                    const float* __restrict__ X,
                                                    float* __restrict__ Y, int nedges) {
    long long t = (long long)blockIdx.x * 256 + threadIdx.x;
    int e = (int)(t >> 6);
    int h = (int)(t & 63);
    if (e >= nedges) return;
    atomicAdd(&Y[rows[e] * N_HID + h], vals[e] * X[cols[e] * N_HID + h]);
}

__global__ __launch_bounds__(256) void leaky_norm_acc(float* __restrict__ Y,
                                                      float* __restrict__ out, int nrows) {
    int row = blockIdx.x * 4 + (threadIdx.x >> 6);
    int h   = threadIdx.x & 63;
    if (row >= nrows) return;
    int idx = row * N_HID + h;
    float v = Y[idx];
    v = (v >= 0.f) ? v : 0.5f * v;
    Y[idx] = v;
    float s = v * v;
#pragma unroll
    for (int off = 32; off > 0; off >>= 1) s += __shfl_xor(s, off, 64);
    out[idx] += v / fmaxf(sqrtf(s), 1e-12f);
}

// ===========================================================================
extern "C" void kernel_launch(void* const* d_in, const int* in_sizes, int n_in,
                              void* d_out, int out_size, void* d_ws, size_t ws_size,
                              hipStream_t stream) {
    const float* user_emb = (const float*)d_in[0];
    const float* item_emb = (const float*)d_in[1];
    const float* ui_w     = (const float*)d_in[2];
    const float* s_w      = (const float*)d_in[3];
    const int*   ui_rows  = (const int*)d_in[4];
    const int*   ui_cols  = (const int*)d_in[5];
    const float* ui_vals  = (const float*)d_in[6];
    const int*   s_rows   = (const int*)d_in[7];
    const int*   s_cols   = (const int*)d_in[8];
    const float* s_vals   = (const float*)d_in[9];

    float* out_ui = (float*)d_out;
    float* out_s  = (float*)d_out + (size_t)N_NODES * N_HID;

    const size_t szUI  = (size_t)N_NODES * N_HID * sizeof(float);     // 64.0 MB
    const size_t szBF  = (size_t)N_TOT   * N_HID * sizeof(short);     // 44.8 MB
    const size_t rsPad = 1400832;                                     // (N_TOT+1)*4 pad
    const size_t lsSz  = 1 << 20;                                     // lstartAll+bucketEnd

    const int uiBlocks = (N_NODES + BR - 1) / BR;    // 3907
    const int sBlocks  = (N_USER  + BR - 1) / BR;    // 1563
    const int nbEC     = (N_TOT * N_HID / 8 + 511) / 512;   // 5469

    const size_t pairsCapPad = (size_t)NBKT * BCAP_PAD * 8;   // 44.8 MB
    const size_t pairsCapStd = (size_t)NBKT * BCAP_STD * 8;   // 33.6 MB

    // embBf is N_TOT rows (combined index space)
    const size_t needPad = 3 * szBF + pairsCapPad + rsPad + lsSz;   // ~182 MB
    const size_t needStd = 3 * szBF + pairsCapStd + rsPad + lsSz;   // ~171 MB

    if (ws_size >= needStd) {
        const bool padded = (ws_size >= needPad);
        const int  bcap   = padded ? BCAP_PAD : BCAP_STD;
        const size_t pairsCap = padded ? pairsCapPad : pairsCapStd;

        unsigned short* embBf = (unsigned short*)d_ws;                   // 350K x 64
        unsigned short* B2    = (unsigned short*)((char*)d_ws + szBF);
        unsigned short* tmp12 = (unsigned short*)((char*)d_ws + 2 * szBF);
        char* p = (char*)d_ws + 3 * szBF;
        ull* pairs     = (ull*)p;            p += pairsCap;
        int* rowStart  = (int*)p;            p += rsPad;
        int* lstartAll = (int*)p;
        int* bucketEnd = lstartAll + (size_t)NBBIN * LSTR;
        ull* pairsA    = (ull*)tmp12;        // staging aliases tmp12 (16MB ≤ 44.8)

        // ---- merged prepass+binning, then per-bucket CSR build ----
        bin_embcast<<<NBBIN + nbEC, 512, 0, stream>>>(ui_rows, ui_cols, ui_vals,
                                                      s_rows, s_cols, s_vals,
                                                      pairsA, lstartAll,
                                                      user_emb, item_emb, embBf);
        if (padded)
            fine_gather2<true><<<NBKT, 512, 0, stream>>>(pairsA, lstartAll,
                                                         rowStart, bucketEnd,
                                                         pairs, bcap);
        else
            fine_gather2<false><<<NBKT, 512, 0, stream>>>(pairsA, lstartAll,
                                                          rowStart, bucketEnd,
                                                          pairs, bcap);

        // ---- 2 fused spmm dispatches (MFMA epilogue) ----
        const int grid = uiBlocks + sBlocks;
        const float* Wui2 = ui_w + N_HID * N_HID;
        const float* Ws2  = s_w  + N_HID * N_HID;
        if (padded) {
            spmm_m<1, true><<<grid, 256, 0, stream>>>(pairs, rowStart, bucketEnd, embBf,
                                                      nullptr, B2, nullptr, tmp12,
                                                      ui_w, s_w, out_ui, out_s, uiBlocks);
            spmm_m<2, true><<<grid, 256, 0, stream>>>(pairs, rowStart, bucketEnd, embBf,
                                                      B2, nullptr, tmp12, nullptr,
                                                      Wui2, Ws2, out_ui, out_s, uiBlocks);
        } else {
            spmm_m<1, false><<<grid, 256, 0, stream>>>(pairs, rowStart, bucketEnd, embBf,
                                                       nullptr, B2, nullptr, tmp12,
                                                       ui_w, s_w, out_ui, out_s, uiBlocks);
            spmm_m<2, false><<<grid, 256, 0, stream>>>(pairs, rowStart, bucketEnd, embBf,
                                                       B2, nullptr, tmp12, nullptr,
                                                       Wui2, Ws2, out_ui, out_s, uiBlocks);
        }
        return;
    }

    // ------------------- fallback: atomic path -------------------
    float* A = (float*)d_ws;
    float* B = (float*)((char*)d_ws + szUI);
    init_concat<<<(N_NODES * N_HID / 4 + 255) / 256, 256, 0, stream>>>(
        user_emb, item_emb, A, out_ui);
    for (int l = 0; l < 2; ++l) {
        gemm64<<<(N_NODES + 255) / 256, 256, 0, stream>>>(
            A, ui_w + l * N_HID * N_HID, B, N_NODES);
        hipMemsetAsync(A, 0, szUI, stream);
        spmm_scatter<<<(int)(((long long)E_UI * 64) / 256), 256, 0, stream>>>(
            ui_rows, ui_cols, ui_vals, B, A, E_UI);
        leaky_norm_acc<<<(N_NODES + 3) / 4, 256, 0, stream>>>(A, out_ui, N_NODES);
    }
    copy2<<<(N_USER * N_HID / 4 + 255) / 256, 256, 0, stream>>>(
        user_emb, A, out_s, N_USER * N_HID / 4);
    const size_t sBytes = (size_t)N_USER * N_HID * sizeof(float);
    for (int l = 0; l < 2; ++l) {
        gemm64<<<(N_USER + 255) / 256, 256, 0, stream>>>(
            A, s_w + l * N_HID * N_HID, B, N_USER);
        hipMemsetAsync(A, 0, sBytes, stream);
        spmm_scatter<<<(int)(((long long)E_S * 64) / 256), 256, 0, stream>>>(
            s_rows, s_cols, s_vals, B, A, E_S);
        leaky_norm_acc<<<(N_USER + 3) / 4, 256, 0, stream>>>(A, out_s, N_USER);
    }
}

// Round 18
// 233.166 us; speedup vs baseline: 1.0453x; 1.0453x over previous
//
#include <hip/hip_runtime.h>

#define N_USER   100000
#define N_ITEM   150000
#define N_NODES  250000
#define N_HID    64
#define E_UI     1000000
#define E_S      1000000
#define N_TOT    (N_NODES + N_USER)      // 350000
#define E_TOT    (E_UI + E_S)            // 2000000

#define BR     64                         // rows per block (spmm)
#define CH     8192                       // edges per binning chunk
#define NBBIN  ((E_TOT + CH - 1) / CH)    // 245
#define RPB    1024                       // rows per coarse bucket
#define RPB_SH 10
#define NBKT   ((N_TOT + RPB - 1) / RPB)  // 342
#define NBKTP  512                        // padded bucket-array size
#define LSTR   344                        // lstartAll row stride (ints)
#define ASTR   72                         // agg LDS row stride (shorts, 144B)
#define BCAP_PAD 16384                    // per-bucket pairs capacity (padded to 8)
#define BCAP_STD 12288                    // per-bucket pairs capacity (unpadded)

typedef unsigned long long ull;
typedef __attribute__((ext_vector_type(8))) short short8v;   // 8 bf16 (4 VGPR)
typedef __attribute__((ext_vector_type(4))) float f32x4;

__device__ __forceinline__ unsigned short f_to_bf(float f) {
    unsigned u = __float_as_uint(f);
    u += 0x7FFF + ((u >> 16) & 1);
    return (unsigned short)(u >> 16);
}
__device__ __forceinline__ float bf_to_f(unsigned short s) {
    return __uint_as_float((unsigned)s << 16);
}
__device__ __forceinline__ unsigned pack_bf2(float a, float b) {
    return (unsigned)f_to_bf(a) | ((unsigned)f_to_bf(b) << 16);
}

// ===========================================================================
// bin_embcast: heterogeneous grid.
//   blocks [0, NBBIN):  per-block private bucket-grouping (zero global atomics)
//   blocks [NBBIN, ..): bf16 cast -> embBf[350K][64] (combined index space)
// ===========================================================================
__global__ __launch_bounds__(512) void bin_embcast(const int* __restrict__ ui_rows,
                                                   const int* __restrict__ ui_cols,
                                                   const float* __restrict__ ui_vals,
                                                   const int* __restrict__ s_rows,
                                                   const int* __restrict__ s_cols,
                                                   const float* __restrict__ s_vals,
                                                   ull* __restrict__ pairsA,
                                                   int* __restrict__ lstartAll,
                                                   const float* __restrict__ u,
                                                   const float* __restrict__ it,
                                                   unsigned short* __restrict__ embBf) {
    __shared__ int hist[NBKTP];
    __shared__ int lstart[NBKTP];
    __shared__ int cnt2[NBKTP];
    const int t = threadIdx.x;

    if ((int)blockIdx.x >= NBBIN) {                 // ---- embcast part ----
        int i = ((int)blockIdx.x - NBBIN) * 512 + t;   // 8 shorts per thread
        const int n8 = N_TOT * N_HID / 8;              // 2.8M
        if (i >= n8) return;
        size_t base = (size_t)i * 8;
        const size_t nu = (size_t)N_USER * N_HID;
        const size_t nn = (size_t)N_NODES * N_HID;
        const float* src = (base < nu) ? u + base
                         : (base < nn) ? it + (base - nu)
                                       : u + (base - nn);
        float4 a = *(const float4*)src;
        float4 b = *(const float4*)(src + 4);
        uint4 o;
        o.x = pack_bf2(a.x, a.y); o.y = pack_bf2(a.z, a.w);
        o.z = pack_bf2(b.x, b.y); o.w = pack_bf2(b.z, b.w);
        *(uint4*)&embBf[base] = o;
        return;
    }

    // ---- binning part ----
    hist[t] = 0; cnt2[t] = 0;
    __syncthreads();

    const int e0 = blockIdx.x * CH;
    const int n  = min(CH, E_TOT - e0);

    // phase 1: bucket histogram (LDS atomics only)
    for (int i = t; i < n; i += 512) {
        int g = e0 + i, r;
        if (g < E_UI) r = ui_rows[g];
        else          r = N_NODES + s_rows[g - E_UI];
        atomicAdd(&hist[r >> RPB_SH], 1);
    }
    __syncthreads();

    // 512-wide exclusive scan (1 elem/thread)
    int v = hist[t];
    lstart[t] = v;
    __syncthreads();
    for (int off = 1; off < NBKTP; off <<= 1) {
        int a = (t >= off) ? lstart[t - off] : 0;
        __syncthreads();
        lstart[t] += a;
        __syncthreads();
    }
    int ex = lstart[t] - v;
    __syncthreads();
    lstart[t] = ex;
    if (t <= NBKT) lstartAll[blockIdx.x * LSTR + t] = ex;   // [NBKT] = n
    __syncthreads();

    // phase 2: re-read + place grouped into private region
    for (int i = t; i < n; i += 512) {
        int g = e0 + i, r, c; float val;
        if (g < E_UI) { r = ui_rows[g];            c = ui_cols[g];            val = ui_vals[g]; }
        else          { int k = g - E_UI;
                        r = N_NODES + s_rows[k];   c = N_NODES + s_cols[k];   val = s_vals[k]; }
        int b = r >> RPB_SH;
        ull entry = ((ull)__float_as_uint(val) << 32) |
                    ((ull)(unsigned)(r & (RPB - 1)) << 19) | (unsigned)c;
        int l = atomicAdd(&cnt2[b], 1);
        pairsA[(size_t)blockIdx.x * CH + lstart[b] + l] = entry;
    }
}

// ===========================================================================
// fine_gather2: one block per bucket. NO global atomics, NO global scan.
//   PAD: row counts rounded to 8 (mask-free spmm loop).
//   bucketEnd[b] = padded data end; last bucket writes rowStart[N_TOT].
// ===========================================================================
template <bool PAD>
__global__ __launch_bounds__(512) void fine_gather2(const ull* __restrict__ pairsA,
                                                    const int* __restrict__ lstartAll,
                                                    int* __restrict__ rowStart,
                                                    int* __restrict__ bucketEnd,
                                                    ull* __restrict__ pairs,
                                                    int bcap) {
    __shared__ int cur[RPB];       // counts -> absolute cursor starts
    __shared__ int sc[RPB];        // scan workspace -> pad-end
    const int b = blockIdx.x, t = threadIdx.x;
    const int r0 = b * RPB;
    const int nr = min(RPB, N_TOT - r0);
    const int base = b * bcap;

    cur[t] = 0; cur[t + 512] = 0;
    __syncthreads();

    const int q    = t >> 4;        // 32 quarters
    const int lane = t & 15;

    // pass A: per-row counts
    for (int blk = q; blk < NBBIN; blk += 32) {
        int s = lstartAll[blk * LSTR + b];
        int e = lstartAll[blk * LSTR + b + 1];
        const ull* src = pairsA + (size_t)blk * CH;
        for (int j = s + lane; j < e; j += 16)
            atomicAdd(&cur[(int)((src[j] >> 19) & (RPB - 1))], 1);
    }
    __syncthreads();

    // padded scan over 1024 counts (2 elems/thread, Hillis–Steele inclusive)
    int c0 = cur[t], c1 = cur[t + 512];
    int p0 = PAD ? ((c0 + 7) & ~7) : c0;
    int p1 = PAD ? ((c1 + 7) & ~7) : c1;
    sc[t] = p0; sc[t + 512] = p1;
    __syncthreads();
    for (int off = 1; off < RPB; off <<= 1) {
        int a = (t >= off) ? sc[t - off] : 0;
        int bb = (t + 512 >= off) ? sc[t + 512 - off] : 0;
        __syncthreads();
        sc[t] += a; sc[t + 512] += bb;
        __syncthreads();
    }
    int inc0 = sc[t], inc1 = sc[t + 512];
    __syncthreads();
    int st0 = base + inc0 - p0;
    int st1 = base + inc1 - p1;
    cur[t] = st0;            cur[t + 512] = st1;            // cursor starts
    sc[t]  = st0 + p0;       sc[t + 512]  = st1 + p1;       // pad-ends
    if (t < nr)        rowStart[r0 + t] = st0;
    if (t + 512 < nr)  rowStart[r0 + t + 512] = st1;
    if (t == 511) {
        bucketEnd[b] = st1 + p1;                           // bucket data end
        if (b == NBKT - 1) rowStart[N_TOT] = st1 + p1;     // global sentinel
    }
    __syncthreads();

    // pass B: scatter (segments are L2-hot from pass A)
    for (int blk = q; blk < NBBIN; blk += 32) {
        int s = lstartAll[blk * LSTR + b];
        int e = lstartAll[blk * LSTR + b + 1];
        const ull* src = pairsA + (size_t)blk * CH;
        for (int j = s + lane; j < e; j += 16) {
            ull en = src[j];
            int rLow = (int)((en >> 19) & (RPB - 1));
            int pos = atomicAdd(&cur[rLow], 1);
            pairs[pos] = (en & 0xFFFFFFFF00000000ull) | (en & 0x7FFFFull);
        }
    }
    if (PAD) {
        __syncthreads();
        for (int i = t; i < nr; i += 512) {
            int end = sc[i];
            for (int j = cur[i]; j < end; ++j) pairs[j] = 0;   // v=0, c=0
        }
    }
}

// ===========================================================================
// spmm_m: quarter-wave gather (bf16, combined index space) + MFMA W-apply.
//   PADDED: rows 8-aligned; single mask-free loop (NO prefetch, NO tail —
//   both proven regressions R9/R15/R17).
//   Bucket-boundary rows clamp their end with bucketEnd (region gaps!).
//   LAYER 1: gather embBf; tmp12 = bf16(emb+n1); B2 = bf16(lv1)
//   LAYER 2: gather B2;    out = f32(tmp12) + n2
// ===========================================================================
template <int LAYER, bool PADDED>
__global__ __launch_bounds__(256) void spmm_m(const ull* __restrict__ pairs,
                                              const int* __restrict__ rowStart,
                                              const int* __restrict__ bucketEnd,
                                              const unsigned short* __restrict__ embBf,
                                              const unsigned short* __restrict__ B2in,
                                              unsigned short* __restrict__ B2out,
                                              const unsigned short* __restrict__ tmp12in,
                                              unsigned short* __restrict__ tmp12out,
                                              const float* __restrict__ Wui,
                                              const float* __restrict__ Wsoc,
                                              float* __restrict__ out_ui,
                                              float* __restrict__ out_s,
                                              int uiBlocks) {
    __shared__ unsigned short Wb[N_HID][ASTR];        // Wb[c][r] = bf16(W[r][c])
    __shared__ unsigned short agg[4][16][ASTR];
    const int tid = threadIdx.x;
    const bool isUI = (int)blockIdx.x < uiBlocks;
    const int bl    = isUI ? blockIdx.x : blockIdx.x - uiBlocks;
    const int rbeg  = isUI ? bl * BR : N_NODES + bl * BR;
    const int rlim  = isUI ? min(BR, N_NODES - bl * BR) : min(BR, N_USER - bl * BR);

    const float* W = isUI ? Wui : Wsoc;
    for (int idx = tid; idx < N_HID * N_HID; idx += 256) {
        int r = idx >> 6, c = idx & 63;
        Wb[c][r] = f_to_bf(W[idx]);
    }
    __syncthreads();

    const int w = tid >> 6;
    if (w * 16 >= rlim) return;             // rlim is always a multiple of 16
    const int s = tid & 15;
    const int g = (tid >> 4) & 3;

    short8v bfrag[4][2];
#pragma unroll
    for (int nt = 0; nt < 4; ++nt)
#pragma unroll
        for (int kt = 0; kt < 2; ++kt)
            bfrag[nt][kt] = *(const short8v*)&Wb[nt * 16 + s][kt * 32 + g * 8];

    const unsigned short* gsrc = (LAYER == 1) ? embBf : B2in;

    int sB[4], eB[4];
#pragma unroll
    for (int i = 0; i < 4; ++i) {
        int r = rbeg + w * 16 + i * 4 + g;
        sB[i] = rowStart[r];
        int e = rowStart[r + 1];
        if (((r + 1) & (RPB - 1)) == 0)     // last row of a bucket: region gap
            e = bucketEnd[r >> RPB_SH];
        eB[i] = e;
    }

    for (int i = 0; i < 4; ++i) {
        float4 acc = make_float4(0.f, 0.f, 0.f, 0.f);
        if (PADDED) {
            for (int j = sB[i]; j < eB[i]; j += 8) {   // mask-free: pads have v=0
                ull p[8];
#pragma unroll
                for (int k = 0; k < 8; ++k) p[k] = pairs[j + k];
                ushort4 raw[8];
#pragma unroll
                for (int k = 0; k < 8; ++k)
                    raw[k] = *(const ushort4*)(gsrc +
                               (size_t)(unsigned)p[k] * N_HID + s * 4);
#pragma unroll
                for (int k = 0; k < 8; ++k) {
                    float v = __uint_as_float((unsigned)(p[k] >> 32));
                    acc.x = fmaf(v, bf_to_f(raw[k].x), acc.x);
                    acc.y = fmaf(v, bf_to_f(raw[k].y), acc.y);
                    acc.z = fmaf(v, bf_to_f(raw[k].z), acc.z);
                    acc.w = fmaf(v, bf_to_f(raw[k].w), acc.w);
                }
            }
        } else {
            int e0 = eB[i];
            for (int j = sB[i]; j < e0; j += 8) {
                int last = e0 - 1;
                ull p[8];
#pragma unroll
                for (int k = 0; k < 8; ++k) p[k] = pairs[min(j + k, last)];
                ushort4 raw[8];
#pragma unroll
                for (int k = 0; k < 8; ++k)
                    raw[k] = *(const ushort4*)(gsrc +
                               (size_t)(unsigned)p[k] * N_HID + s * 4);
#pragma unroll
                for (int k = 0; k < 8; ++k) {
                    float v = (j + k < e0) ? __uint_as_float((unsigned)(p[k] >> 32)) : 0.f;
                    acc.x = fmaf(v, bf_to_f(raw[k].x), acc.x);
                    acc.y = fmaf(v, bf_to_f(raw[k].y), acc.y);
                    acc.z = fmaf(v, bf_to_f(raw[k].z), acc.z);
                    acc.w = fmaf(v, bf_to_f(raw[k].w), acc.w);
                }
            }
        }
        uint2 pk;
        pk.x = pack_bf2(acc.x, acc.y);
        pk.y = pack_bf2(acc.z, acc.w);
        *(uint2*)&agg[w][i * 4 + g][s * 4] = pk;
    }
    asm volatile("s_waitcnt lgkmcnt(0)" ::: "memory");
    __builtin_amdgcn_sched_barrier(0);

    // ---- MFMA: z(16x64) = agg(16x64) @ W(64x64) ----
    short8v a0 = *(const short8v*)&agg[w][s][g * 8];
    short8v a1 = *(const short8v*)&agg[w][s][32 + g * 8];
    f32x4 c[4];
    const f32x4 zero4 = {0.f, 0.f, 0.f, 0.f};
#pragma unroll
    for (int nt = 0; nt < 4; ++nt) {
        c[nt] = __builtin_amdgcn_mfma_f32_16x16x32_bf16(a0, bfrag[nt][0], zero4, 0, 0, 0);
        c[nt] = __builtin_amdgcn_mfma_f32_16x16x32_bf16(a1, bfrag[nt][1], c[nt], 0, 0, 0);
    }

    // ---- leaky + row l2norm (C/D: col = nt*16+s, row = g*4+r) ----
    float lv[4][4];
    float ss[4] = {0.f, 0.f, 0.f, 0.f};
#pragma unroll
    for (int nt = 0; nt < 4; ++nt)
#pragma unroll
        for (int r = 0; r < 4; ++r) {
            float z = c[nt][r];
            float l = (z >= 0.f) ? z : 0.5f * z;
            lv[nt][r] = l;
            ss[r] = fmaf(l, l, ss[r]);
        }
#pragma unroll
    for (int r = 0; r < 4; ++r) {
        float t = ss[r];
        t += __shfl_xor(t, 1, 64);
        t += __shfl_xor(t, 2, 64);
        t += __shfl_xor(t, 4, 64);
        t += __shfl_xor(t, 8, 64);
        ss[r] = 1.f / fmaxf(sqrtf(t), 1e-12f);
    }

    // ---- outputs ----
#pragma unroll
    for (int r = 0; r < 4; ++r) {
        int R = rbeg + w * 16 + g * 4 + r;
        if (LAYER == 1) {
#pragma unroll
            for (int nt = 0; nt < 4; ++nt) {
                int col = nt * 16 + s;
                float eb = bf_to_f(embBf[(size_t)R * N_HID + col]);   // combined space
                tmp12out[(size_t)R * N_HID + col] = f_to_bf(fmaf(lv[nt][r], ss[r], eb));
                B2out[(size_t)R * N_HID + col]    = f_to_bf(lv[nt][r]);
            }
        } else {
            float* op = isUI ? out_ui + (size_t)R * N_HID
                             : out_s  + (size_t)(R - N_NODES) * N_HID;
#pragma unroll
            for (int nt = 0; nt < 4; ++nt) {
                int col = nt * 16 + s;
                float tb = bf_to_f(tmp12in[(size_t)R * N_HID + col]);
                op[col] = fmaf(lv[nt][r], ss[r], tb);
            }
        }
    }
}

// ===========================================================================
// Atomic fallback (only if ws too small for the sorted path)
// ===========================================================================
__global__ __launch_bounds__(256) void init_concat(const float* __restrict__ u,
                                                   const float* __restrict__ it,
                                                   float* __restrict__ A,
                                                   float* __restrict__ out) {
    int i = blockIdx.x * 256 + threadIdx.x;
    const int nu4 = N_USER * N_HID / 4;
    const int nt4 = N_NODES * N_HID / 4;
    if (i >= nt4) return;
    float4 v = (i < nu4) ? ((const float4*)u)[i] : ((const float4*)it)[i - nu4];
    ((float4*)A)[i]   = v;
    ((float4*)out)[i] = v;
}

__global__ __launch_bounds__(256) void copy2(const float* __restrict__ src,
                                             float* __restrict__ d0,
                                             float* __restrict__ d1, int n4) {
    int i = blockIdx.x * 256 + threadIdx.x;
    if (i >= n4) return;
    float4 v = ((const float4*)src)[i];
    ((float4*)d0)[i] = v;
    ((float4*)d1)[i] = v;
}

__global__ __launch_bounds__(256) void gemm64(const float* __restrict__ X,
                                              const float* __restrict__ W,
                                              float* __restrict__ Y, int nrows) {
    __shared__ float Ws[N_HID * N_HID];
    int tid = threadIdx.x;
#pragma unroll
    for (int c = 0; c < 16; ++c) Ws[c * 256 + tid] = W[c * 256 + tid];
    __syncthreads();
    int row = blockIdx.x * 256 + tid;
    if (row >= nrows) return;
    float x[N_HID];
    const float4* xr = (const float4*)(X + (size_t)row * N_HID);
#pragma unroll
    for (int c = 0; c < 16; ++c) {
        float4 v = xr[c];
        x[4*c+0] = v.x; x[4*c+1] = v.y; x[4*c+2] = v.z; x[4*c+3] = v.w;
    }
    float4* y4 = (float4*)(Y + (size_t)row * N_HID);
    for (int jc = 0; jc < 16; ++jc) {
        float4 a = make_float4(0.f,0.f,0.f,0.f);
#pragma unroll
        for (int k = 0; k < N_HID; ++k) {
            float4 wv = *((const float4*)&Ws[k * N_HID + jc * 4]);
            a.x += x[k]*wv.x; a.y += x[k]*wv.y; a.z += x[k]*wv.z; a.w += x[k]*wv.w;
        }
        y4[jc] = a;
    }
}

__global__ __launch_bounds__(256) void spmm_scatter(const int* __restrict__ rows,
                                                    const int* __restrict__ cols,
                                                    const float* __restrict__ vals,
                                                    const float* __restrict__ X,
                                                    float* __restrict__ Y, int nedges) {
    long long t = (long long)blockIdx.x * 256 + threadIdx.x;
    int e = (int)(t >> 6);
    int h = (int)(t & 63);
    if (e >= nedges) return;
    atomicAdd(&Y[rows[e] * N_HID + h], vals[e] * X[cols[e] * N_HID + h]);
}

__global__ __launch_bounds__(256) void leaky_norm_acc(float* __restrict__ Y,
                                                      float* __restrict__ out, int nrows) {
    int row = blockIdx.x * 4 + (threadIdx.x >> 6);
    int h   = threadIdx.x & 63;
    if (row >= nrows) return;
    int idx = row * N_HID + h;
    float v = Y[idx];
    v = (v >= 0.f) ? v : 0.5f * v;
    Y[idx] = v;
    float s = v * v;
#pragma unroll
    for (int off = 32; off > 0; off >>= 1) s += __shfl_xor(s, off, 64);
    out[idx] += v / fmaxf(sqrtf(s), 1e-12f);
}

// ===========================================================================
extern "C" void kernel_launch(void* const* d_in, const int* in_sizes, int n_in,
                              void* d_out, int out_size, void* d_ws, size_t ws_size,
                              hipStream_t stream) {
    const float* user_emb = (const float*)d_in[0];
    const float* item_emb = (const float*)d_in[1];
    const float* ui_w     = (const float*)d_in[2];
    const float* s_w      = (const float*)d_in[3];
    const int*   ui_rows  = (const int*)d_in[4];
    const int*   ui_cols  = (const int*)d_in[5];
    const float* ui_vals  = (const float*)d_in[6];
    const int*   s_rows   = (const int*)d_in[7];
    const int*   s_cols   = (const int*)d_in[8];
    const float* s_vals   = (const float*)d_in[9];

    float* out_ui = (float*)d_out;
    float* out_s  = (float*)d_out + (size_t)N_NODES * N_HID;

    const size_t szUI  = (size_t)N_NODES * N_HID * sizeof(float);     // 64.0 MB
    const size_t szBF  = (size_t)N_TOT   * N_HID * sizeof(short);     // 44.8 MB
    const size_t rsPad = 1400832;                                     // (N_TOT+1)*4 pad
    const size_t lsSz  = 1 << 20;                                     // lstartAll+bucketEnd

    const int uiBlocks = (N_NODES + BR - 1) / BR;    // 3907
    const int sBlocks  = (N_USER  + BR - 1) / BR;    // 1563
    const int nbEC     = (N_TOT * N_HID / 8 + 511) / 512;   // 5469

    const size_t pairsCapPad = (size_t)NBKT * BCAP_PAD * 8;   // 44.8 MB
    const size_t pairsCapStd = (size_t)NBKT * BCAP_STD * 8;   // 33.6 MB

    // embBf is N_TOT rows (combined index space)
    const size_t needPad = 3 * szBF + pairsCapPad + rsPad + lsSz;   // ~182 MB
    const size_t needStd = 3 * szBF + pairsCapStd + rsPad + lsSz;   // ~171 MB

    if (ws_size >= needStd) {
        const bool padded = (ws_size >= needPad);
        const int  bcap   = padded ? BCAP_PAD : BCAP_STD;
        const size_t pairsCap = padded ? pairsCapPad : pairsCapStd;

        unsigned short* embBf = (unsigned short*)d_ws;                   // 350K x 64
        unsigned short* B2    = (unsigned short*)((char*)d_ws + szBF);
        unsigned short* tmp12 = (unsigned short*)((char*)d_ws + 2 * szBF);
        char* p = (char*)d_ws + 3 * szBF;
        ull* pairs     = (ull*)p;            p += pairsCap;
        int* rowStart  = (int*)p;            p += rsPad;
        int* lstartAll = (int*)p;
        int* bucketEnd = lstartAll + (size_t)NBBIN * LSTR;
        ull* pairsA    = (ull*)tmp12;        // staging aliases tmp12 (16MB ≤ 44.8)

        // ---- merged prepass+binning, then per-bucket CSR build ----
        bin_embcast<<<NBBIN + nbEC, 512, 0, stream>>>(ui_rows, ui_cols, ui_vals,
                                                      s_rows, s_cols, s_vals,
                                                      pairsA, lstartAll,
                                                      user_emb, item_emb, embBf);
        if (padded)
            fine_gather2<true><<<NBKT, 512, 0, stream>>>(pairsA, lstartAll,
                                                         rowStart, bucketEnd,
                                                         pairs, bcap);
        else
            fine_gather2<false><<<NBKT, 512, 0, stream>>>(pairsA, lstartAll,
                                                          rowStart, bucketEnd,
                                                          pairs, bcap);

        // ---- 2 fused spmm dispatches (MFMA epilogue) ----
        const int grid = uiBlocks + sBlocks;
        const float* Wui2 = ui_w + N_HID * N_HID;
        const float* Ws2  = s_w  + N_HID * N_HID;
        if (padded) {
            spmm_m<1, true><<<grid, 256, 0, stream>>>(pairs, rowStart, bucketEnd, embBf,
                                                      nullptr, B2, nullptr, tmp12,
                                                      ui_w, s_w, out_ui, out_s, uiBlocks);
            spmm_m<2, true><<<grid, 256, 0, stream>>>(pairs, rowStart, bucketEnd, embBf,
                                                      B2, nullptr, tmp12, nullptr,
                                                      Wui2, Ws2, out_ui, out_s, uiBlocks);
        } else {
            spmm_m<1, false><<<grid, 256, 0, stream>>>(pairs, rowStart, bucketEnd, embBf,
                                                       nullptr, B2, nullptr, tmp12,
                                                       ui_w, s_w, out_ui, out_s, uiBlocks);
            spmm_m<2, false><<<grid, 256, 0, stream>>>(pairs, rowStart, bucketEnd, embBf,
                                                       B2, nullptr, tmp12, nullptr,
                                                       Wui2, Ws2, out_ui, out_s, uiBlocks);
        }
        return;
    }

    // ------------------- fallback: atomic path -------------------
    float* A = (float*)d_ws;
    float* B = (float*)((char*)d_ws + szUI);
    init_concat<<<(N_NODES * N_HID / 4 + 255) / 256, 256, 0, stream>>>(
        user_emb, item_emb, A, out_ui);
    for (int l = 0; l < 2; ++l) {
        gemm64<<<(N_NODES + 255) / 256, 256, 0, stream>>>(
            A, ui_w + l * N_HID * N_HID, B, N_NODES);
        hipMemsetAsync(A, 0, szUI, stream);
        spmm_scatter<<<(int)(((long long)E_UI * 64) / 256), 256, 0, stream>>>(
            ui_rows, ui_cols, ui_vals, B, A, E_UI);
        leaky_norm_acc<<<(N_NODES + 3) / 4, 256, 0, stream>>>(A, out_ui, N_NODES);
    }
    copy2<<<(N_USER * N_HID / 4 + 255) / 256, 256, 0, stream>>>(
        user_emb, A, out_s, N_USER * N_HID / 4);
    const size_t sBytes = (size_t)N_USER * N_HID * sizeof(float);
    for (int l = 0; l < 2; ++l) {
        gemm64<<<(N_USER + 255) / 256, 256, 0, stream>>>(
            A, s_w + l * N_HID * N_HID, B, N_USER);
        hipMemsetAsync(A, 0, sBytes, stream);
        spmm_scatter<<<(int)(((long long)E_S * 64) / 256), 256, 0, stream>>>(
            s_rows, s_cols, s_vals, B, A, E_S);
        leaky_norm_acc<<<(N_USER + 3) / 4, 256, 0, stream>>>(A, out_s, N_USER);
    }
}